// Round 8
// baseline (189.551 us; speedup 1.0000x reference)
//
#include <hip/hip_runtime.h>
#include <hip/hip_bf16.h>
#include <math.h>

#define FEATN 12544
#define NIMG 1024

typedef __attribute__((ext_vector_type(8))) short short8;
typedef __attribute__((ext_vector_type(4))) float f32x4;

// ---- ws byte offsets (all sizes in BYTES; bf16 regions are 2 B/elem) ----
#define OFF_W1F   0            //  2048 bf16  =     4096 B   conv1 B-frag table
#define OFF_W2F   6144         //  32768 bf16 =    65536 B   conv2 B-frag table
#define OFF_WBBF  71680        //  1605632 bf16 = 3211264 B  gemm_u B-frag table
#define OFF_H1B   3282944      //  1024*28800 bf16 = 58982400 B
#define OFF_FEATB 62265344     //  1024*12544 bf16 = 25690112 B
#define OFF_U     87955456     //  131072 f32 = 524288 B   (layout [t][b][128])
#define OFF_PART  88479744     //  28*131072 f32 = 14680064 B
#define OFF_HID   103159808    //  1024 f32 = 4096 B
#define OFF_WHF   103163904    //  8192 bf16 = 16384 B   rnn Wh B-frag table
#define OFF_WGF   103180288    //  32768 bf16 = 65536 B  rnn [ff1|ff2|ta|tb] B-frag table
#define WS_BYTES  103245824

__device__ __forceinline__ unsigned short f2bf(float v) {
    union { float f; unsigned int u; } c; c.f = v;
    unsigned int r = c.u + 0x7FFFu + ((c.u >> 16) & 1u);   // RNE
    return (unsigned short)(r >> 16);
}
__device__ __forceinline__ float bf2f(unsigned short h) {
    union { unsigned int u; float f; } c; c.u = ((unsigned int)h) << 16;
    return c.f;
}

__device__ __forceinline__ float fast_tanh(float x) {
    x = fminf(fmaxf(x, -15.f), 15.f);
    float e = __expf(2.f * x);
    return (e - 1.f) * __builtin_amdgcn_rcpf(e + 1.f);
}
__device__ __forceinline__ float fast_sigmoid(float x) {
    x = fminf(fmaxf(x, -30.f), 30.f);
    return __builtin_amdgcn_rcpf(1.f + __expf(-x));
}

// raw workgroup barrier: LDS-visibility only, leaves vmcnt in flight (m201 pattern)
__device__ __forceinline__ void sbar() {
    __builtin_amdgcn_sched_barrier(0);
    asm volatile("s_waitcnt lgkmcnt(0)" ::: "memory");
    __builtin_amdgcn_sched_barrier(0);
    __builtin_amdgcn_s_barrier();
    __builtin_amdgcn_sched_barrier(0);
}

// unpack 8 packed dwords {lo16<<16|hi16} -> hi-frag, lo-frag (short8)
__device__ __forceinline__ void unpack8(uint4 a, uint4 b, short8* hi, short8* lo) {
    union { unsigned int u[4]; short8 s; } H, L;
    H.u[0] = __builtin_amdgcn_perm(a.y, a.x, 0x05040100u);
    H.u[1] = __builtin_amdgcn_perm(a.w, a.z, 0x05040100u);
    H.u[2] = __builtin_amdgcn_perm(b.y, b.x, 0x05040100u);
    H.u[3] = __builtin_amdgcn_perm(b.w, b.z, 0x05040100u);
    L.u[0] = __builtin_amdgcn_perm(a.y, a.x, 0x07060302u);
    L.u[1] = __builtin_amdgcn_perm(a.w, a.z, 0x07060302u);
    L.u[2] = __builtin_amdgcn_perm(b.y, b.x, 0x07060302u);
    L.u[3] = __builtin_amdgcn_perm(b.w, b.z, 0x07060302u);
    *hi = H.s; *lo = L.s;
}

// ---------------- prep: conv1 weights -> MFMA B-frag layout (bf16) ----------------
__global__ void prep_w1f(const float* __restrict__ w1, unsigned short* __restrict__ w1f) {
    int i = blockIdx.x * blockDim.x + threadIdx.x;   // 2048
    if (i >= 2048) return;
    int j = i & 7, lane = (i >> 3) & 63, nt = (i >> 9) & 1, kstep = (i >> 10) & 1;
    int oc = nt * 16 + (lane & 15);
    int ky = (lane >> 4) & 3, kx = j & 3;
    float v;
    if (kstep == 0) {
        int ic = j >> 2;
        v = w1[oc * 48 + ic * 16 + ky * 4 + kx];
    } else {
        v = (j >> 2) == 0 ? w1[oc * 48 + 32 + ky * 4 + kx] : 0.f;
    }
    w1f[i] = f2bf(v);
}

// ---------------- prep: conv2 weights -> MFMA B-frag layout (bf16) ----------------
__global__ void prep_w2f(const float* __restrict__ w2, unsigned short* __restrict__ w2f) {
    int i = blockIdx.x * blockDim.x + threadIdx.x;   // 32768
    int j = i & 7, lane = (i >> 3) & 63, kstep = (i >> 9) & 15, nt = i >> 13;
    int oc = nt * 16 + (lane & 15);
    int ic = 2 * kstep + (j >> 2);
    int ky = lane >> 4, kx = j & 3;
    w2f[i] = f2bf(w2[oc * 512 + ic * 16 + ky * 4 + kx]);
}

// ---------------- prep: Wbb(feat part) -> MFMA B-frag layout (bf16) ----------------
__global__ void prep_wbbf(const float* __restrict__ Wbb, unsigned short* __restrict__ Wbbf) {
    int i = blockIdx.x * blockDim.x + threadIdx.x;   // 1605632
    int j = i & 7, lane = (i >> 3) & 63, nt = (i >> 9) & 7, kstep = i >> 12;
    int f = kstep * 32 + (lane >> 4) * 8 + j;
    int col = nt * 16 + (lane & 15);
    Wbbf[i] = f2bf(Wbb[(size_t)f * 128 + col]);
}

// ---------------- prep: Wh (= Wbb[12544:]) -> B-frags: K=64 (2 ks), N=128 (8 nt) ----------------
__global__ void prep_whf(const float* __restrict__ Wbb, unsigned short* __restrict__ whf) {
    int i = blockIdx.x * blockDim.x + threadIdx.x;   // 8192
    if (i >= 8192) return;
    int j = i & 7, lane = (i >> 3) & 63, nt = (i >> 9) & 7, kstep = (i >> 12) & 1;
    int k = kstep * 32 + ((lane >> 4) & 3) * 8 + j;          // hid dim 0..63
    int col = nt * 16 + (lane & 15);                          // z col 0..127
    whf[i] = f2bf(Wbb[(size_t)(FEATN + k) * 128 + col]);
}

// ---------------- prep: [Wff1|Wff2|Wta|Wtb] -> B-frags: K=128 (4 ks), N=256 (16 nt) ----------------
__global__ void prep_wgf(const float* __restrict__ Wff1, const float* __restrict__ Wff2,
                         const float* __restrict__ Wta,  const float* __restrict__ Wtb,
                         unsigned short* __restrict__ wgf) {
    int i = blockIdx.x * blockDim.x + threadIdx.x;   // 32768
    int j = i & 7, lane = (i >> 3) & 63, nt = (i >> 9) & 15, kstep = (i >> 13) & 3;
    int k = kstep * 32 + ((lane >> 4) & 3) * 8 + j;          // z dim 0..127
    int m = nt >> 2;
    int c = (nt & 3) * 16 + (lane & 15);                      // col 0..63
    const float* Wm = (m == 0) ? Wff1 : (m == 1) ? Wff2 : (m == 2) ? Wta : Wtb;
    wgf[i] = f2bf(Wm[k * 64 + c]);
}

// ---------------- conv1 as implicit GEMM, bf16 MFMA ----------------
__global__ __launch_bounds__(256) void conv1_mfma(const float* __restrict__ x,
                                                  const float* __restrict__ b1,
                                                  const unsigned short* __restrict__ w1f,
                                                  unsigned short* __restrict__ h1b) {
    __shared__ unsigned int xs32[3 * 2046];        // 24.6 KB
    int img = blockIdx.x;
    int tid = threadIdx.x;
    const float* xg = x + (size_t)img * 11532;
    for (int d = tid; d < 5766; d += 256) {
        int c = d / 1922, r = d - c * 1922;
        int y = r / 31, xd = r - y * 31;
        const float* s = xg + c * 3844 + y * 62 + xd * 2;
        unsigned int lo = f2bf(s[0]), hi = f2bf(s[1]);
        xs32[c * 2046 + y * 33 + xd] = lo | (hi << 16);
    }
    __syncthreads();

    int lane = tid & 63, wid = tid >> 6;
    int rowl = lane & 15, g = lane >> 4;

    short8 bfr[2][2];
    #pragma unroll
    for (int ks = 0; ks < 2; ++ks)
        #pragma unroll
        for (int nt = 0; nt < 2; ++nt)
            bfr[ks][nt] = *(const short8*)(w1f + (((ks * 2 + nt) * 64 + lane) << 3));
    float bias0 = b1[rowl], bias1 = b1[16 + rowl];

    for (int i = 0; i < 15; ++i) {
        int mtile = wid + 4 * i;
        if (mtile >= 57) break;
        int m = mtile * 16 + rowl; if (m > 899) m = 899;
        int oy = m / 30, ox = m - oy * 30;
        int dof = (2 * oy + g) * 33 + ox;
        union { unsigned int u[4]; short8 s; } af0, af1;
        af0.u[0] = xs32[dof];          af0.u[1] = xs32[dof + 1];
        af0.u[2] = xs32[2046 + dof];   af0.u[3] = xs32[2046 + dof + 1];
        af1.u[0] = xs32[4092 + dof];   af1.u[1] = xs32[4092 + dof + 1];
        af1.u[2] = 0;                  af1.u[3] = 0;
        f32x4 acc0 = (f32x4){0.f, 0.f, 0.f, 0.f};
        f32x4 acc1 = (f32x4){0.f, 0.f, 0.f, 0.f};
        acc0 = __builtin_amdgcn_mfma_f32_16x16x32_bf16(af0.s, bfr[0][0], acc0, 0, 0, 0);
        acc0 = __builtin_amdgcn_mfma_f32_16x16x32_bf16(af1.s, bfr[1][0], acc0, 0, 0, 0);
        acc1 = __builtin_amdgcn_mfma_f32_16x16x32_bf16(af0.s, bfr[0][1], acc1, 0, 0, 0);
        acc1 = __builtin_amdgcn_mfma_f32_16x16x32_bf16(af1.s, bfr[1][1], acc1, 0, 0, 0);
        int sp0 = mtile * 16 + g * 4;
        #pragma unroll
        for (int nt = 0; nt < 2; ++nt) {
            f32x4 a = nt ? acc1 : acc0;
            int oc = nt * 16 + rowl;
            float bias = nt ? bias1 : bias0;
            unsigned short pk[4];
            #pragma unroll
            for (int r = 0; r < 4; ++r) pk[r] = f2bf(fmaxf(a[r] + bias, 0.f));
            unsigned short* dstp = h1b + (size_t)img * 28800 + oc * 900 + sp0;
            if (sp0 + 3 < 900) {
                *(uint2*)dstp = *(uint2*)pk;
            } else {
                #pragma unroll
                for (int r = 0; r < 4; ++r) if (sp0 + r < 900) dstp[r] = pk[r];
            }
        }
    }
}

// ---------------- conv2 as implicit GEMM, bf16 MFMA ----------------
__global__ __launch_bounds__(256) void conv2_mfma(const unsigned short* __restrict__ h1b,
                                                  const float* __restrict__ b2,
                                                  const unsigned short* __restrict__ w2f,
                                                  unsigned short* __restrict__ featb) {
    __shared__ unsigned short h1s[32 * 30 * 32];   // [ic][y][x pad 32] = 60 KB
    int img = blockIdx.x;
    int tid = threadIdx.x;
    {
        const unsigned int* src = (const unsigned int*)(h1b + (size_t)img * 28800);
        unsigned int* dst = (unsigned int*)h1s;
        for (int d = tid; d < 14400; d += 256) {
            int ic = d / 450, r = d - ic * 450;
            int y = r / 15, x2 = r - y * 15;
            dst[(ic * 30 + y) * 16 + x2] = src[d];
        }
    }
    __syncthreads();
    int lane = tid & 63, wid = tid >> 6;
    int rowl = lane & 15, g = lane >> 4;

    f32x4 acc[4][4];
    #pragma unroll
    for (int i = 0; i < 4; ++i)
        #pragma unroll
        for (int nt = 0; nt < 4; ++nt) acc[i][nt] = (f32x4){0.f, 0.f, 0.f, 0.f};

    int dofs[4];
    #pragma unroll
    for (int i = 0; i < 4; ++i) {
        int mtile = wid + 4 * i;
        int m = mtile * 16 + rowl; if (m > 195) m = 195;
        int oy = m / 14, ox = m - oy * 14;
        int y = 2 * oy + g, x0 = 2 * ox;
        dofs[i] = y * 16 + (x0 >> 1);
    }
    const unsigned int* lds32 = (const unsigned int*)h1s;

    #pragma unroll 4
    for (int kstep = 0; kstep < 16; ++kstep) {
        short8 bfr[4];
        #pragma unroll
        for (int nt = 0; nt < 4; ++nt)
            bfr[nt] = *(const short8*)(w2f + (((nt * 16 + kstep) * 64 + lane) << 3));
        int icb = kstep * 960;
        #pragma unroll
        for (int i = 0; i < 4; ++i) {
            int mtile = wid + 4 * i;
            if (mtile < 13) {
                int dof = icb + dofs[i];
                union { unsigned int u[4]; short8 s; } af;
                af.u[0] = lds32[dof];
                af.u[1] = lds32[dof + 1];
                af.u[2] = lds32[dof + 480];
                af.u[3] = lds32[dof + 481];
                #pragma unroll
                for (int nt = 0; nt < 4; ++nt)
                    acc[i][nt] = __builtin_amdgcn_mfma_f32_16x16x32_bf16(af.s, bfr[nt], acc[i][nt], 0, 0, 0);
            }
        }
    }
    #pragma unroll
    for (int i = 0; i < 4; ++i) {
        int mtile = wid + 4 * i;
        if (mtile >= 13) continue;
        int sp0 = mtile * 16 + g * 4;
        #pragma unroll
        for (int nt = 0; nt < 4; ++nt) {
            int oc = nt * 16 + rowl;
            float bias = b2[oc];
            unsigned short pk[4];
            #pragma unroll
            for (int r = 0; r < 4; ++r)
                pk[r] = f2bf(fmaxf(acc[i][nt][r] + bias, 0.f));
            unsigned short* dstp = featb + (size_t)img * 12544 + oc * 196 + sp0;
            if (sp0 + 3 < 196) {
                *(uint2*)dstp = *(uint2*)pk;
            } else {
                #pragma unroll
                for (int r = 0; r < 4; ++r) if (sp0 + r < 196) dstp[r] = pk[r];
            }
        }
    }
}

// ---------------- u = feat @ W_in : bf16 MFMA, split-K=28 ----------------
__global__ __launch_bounds__(256) void gemm_u_mfma(const unsigned short* __restrict__ featb,
                                                   const unsigned short* __restrict__ Wbbf,
                                                   float* __restrict__ part) {
    int tid = threadIdx.x, lane = tid & 63, wid = tid >> 6;
    int rowl = lane & 15, g = lane >> 4;
    int m0 = blockIdx.x * 64 + wid * 16;
    int ks0 = blockIdx.y * 14;
    f32x4 acc[8];
    #pragma unroll
    for (int nt = 0; nt < 8; ++nt) acc[nt] = (f32x4){0.f, 0.f, 0.f, 0.f};
    const unsigned short* arow = featb + (size_t)(m0 + rowl) * FEATN + g * 8;
    #pragma unroll 2
    for (int kk = 0; kk < 14; ++kk) {
        int kstep = ks0 + kk;
        short8 afr = *(const short8*)(arow + kstep * 32);
        #pragma unroll
        for (int nt = 0; nt < 8; ++nt) {
            short8 bfr = *(const short8*)(Wbbf + ((((size_t)kstep * 8 + nt) * 64 + lane) << 3));
            acc[nt] = __builtin_amdgcn_mfma_f32_16x16x32_bf16(afr, bfr, acc[nt], 0, 0, 0);
        }
    }
    float* pg = part + (size_t)blockIdx.y * 131072;
    #pragma unroll
    for (int nt = 0; nt < 8; ++nt)
        #pragma unroll
        for (int r = 0; r < 4; ++r)
            pg[(m0 + g * 4 + r) * 128 + nt * 16 + rowl] = acc[nt][r];
}

// reduce into u laid out [t][b][128]
__global__ void reduce_u(const float* __restrict__ part, const float* __restrict__ bbb,
                         float* __restrict__ u) {
    int o = blockIdx.x * 256 + threadIdx.x;   // 131072 total
    int c = o & 127, b = (o >> 7) & 15, t = o >> 11;
    int m = b * 64 + t;
    float s = bbb[c];
    #pragma unroll
    for (int ks = 0; ks < 28; ++ks) s += part[(size_t)ks * 131072 + m * 128 + c];
    u[o] = s;
}

// ---------------- liquid RNN scan: batched MFMA, packed hi/lo dwords, raw barriers ----------------
// zP[row][col] / hidP[row][col] hold dword = lo16<<16 | hi16 (split-bf16 of the f32 value).
// Rows padded (132 / 68 dwords) -> <=2-way bank aliasing on all access patterns.
// u prefetched depth-2 into registers; barriers never drain vmcnt.
__global__ __launch_bounds__(256, 1) void rnn_mfma(const float* __restrict__ u,
                                                   const unsigned short* __restrict__ whf,
                                                   const unsigned short* __restrict__ wgf,
                                                   const float* __restrict__ bff1,
                                                   const float* __restrict__ bff2,
                                                   const float* __restrict__ bta,
                                                   const float* __restrict__ btb,
                                                   float* __restrict__ hid_out) {
    __shared__ unsigned int zP[16 * 132];      // 8448 B
    __shared__ unsigned int hidP[16 * 68];     // 4352 B
    int tid = threadIdx.x, lane = tid & 63, w = tid >> 6;
    int rowl = lane & 15, g = lane >> 4;

    for (int idx = tid; idx < 16 * 68; idx += 256) hidP[idx] = 0;

    // B-fragments -> registers (once)
    short8 wh_r[2][2];   // [kstep][ntl], nt_abs = 2w + ntl
    #pragma unroll
    for (int ks = 0; ks < 2; ++ks)
        #pragma unroll
        for (int ntl = 0; ntl < 2; ++ntl)
            wh_r[ks][ntl] = *(const short8*)(whf + (((ks * 8 + 2 * w + ntl) * 64 + lane) << 3));
    short8 wg_r[4][4];   // [m][kstep], nt_abs = 4m + w
    #pragma unroll
    for (int m = 0; m < 4; ++m)
        #pragma unroll
        for (int ks = 0; ks < 4; ++ks)
            wg_r[m][ks] = *(const short8*)(wgf + (((ks * 16 + 4 * m + w) * 64 + lane) << 3));

    int cc = w * 16 + rowl;                   // this lane's phase-2 column
    float bias1 = bff1[cc], bias2 = bff2[cc], biast = bta[cc] + btb[cc];

    // per-thread u base; element (t, ntl, r) at ubase[t*2048 + r*128 + ntl*16]
    const float* ubase = u + (size_t)(g * 4) * 128 + (2 * w) * 16 + rowl;
    float upfA[8], upfB[8];
    #pragma unroll
    for (int i = 0; i < 8; ++i) upfA[i] = ubase[(i & 3) * 128 + (i >> 2) * 16];
    #pragma unroll
    for (int i = 0; i < 8; ++i) upfB[i] = ubase[2048 + (i & 3) * 128 + (i >> 2) * 16];

    sbar();

    float hidv[4];

#define RNN_STEP(T, UPF)                                                                 \
    {                                                                                    \
        /* ---- Phase 1: z = lecun_tanh(u_t + hid @ Wh) ---- */                          \
        short8 ah[2], al[2];                                                             \
        _Pragma("unroll")                                                                \
        for (int ks = 0; ks < 2; ++ks) {                                                 \
            const unsigned int* p = &hidP[rowl * 68 + ks * 32 + g * 8];                  \
            unpack8(*(const uint4*)p, *(const uint4*)(p + 4), &ah[ks], &al[ks]);         \
        }                                                                                \
        f32x4 za[2], zb[2];                                                              \
        _Pragma("unroll")                                                                \
        for (int ntl = 0; ntl < 2; ++ntl) {                                              \
            za[ntl] = (f32x4){UPF[ntl * 4], UPF[ntl * 4 + 1], UPF[ntl * 4 + 2], UPF[ntl * 4 + 3]}; \
            za[ntl] = __builtin_amdgcn_mfma_f32_16x16x32_bf16(al[0], wh_r[0][ntl], za[ntl], 0, 0, 0); \
            za[ntl] = __builtin_amdgcn_mfma_f32_16x16x32_bf16(al[1], wh_r[1][ntl], za[ntl], 0, 0, 0); \
            zb[ntl] = (f32x4){0.f, 0.f, 0.f, 0.f};                                       \
            zb[ntl] = __builtin_amdgcn_mfma_f32_16x16x32_bf16(ah[0], wh_r[0][ntl], zb[ntl], 0, 0, 0); \
            zb[ntl] = __builtin_amdgcn_mfma_f32_16x16x32_bf16(ah[1], wh_r[1][ntl], zb[ntl], 0, 0, 0); \
        }                                                                                \
        /* issue u prefetch for T+2 (stays in flight across raw barriers) */             \
        {                                                                                \
            int tn = (T) + 2; if (tn > 63) tn = 63;                                      \
            _Pragma("unroll")                                                            \
            for (int i = 0; i < 8; ++i)                                                  \
                UPF[i] = ubase[(size_t)tn * 2048 + (i & 3) * 128 + (i >> 2) * 16];       \
        }                                                                                \
        _Pragma("unroll")                                                                \
        for (int ntl = 0; ntl < 2; ++ntl) {                                              \
            f32x4 zs = za[ntl] + zb[ntl];                                                \
            _Pragma("unroll")                                                            \
            for (int r = 0; r < 4; ++r) {                                                \
                float zv = 1.7159f * fast_tanh(0.666f * zs[r]);                          \
                unsigned int hi = f2bf(zv);                                              \
                unsigned int lo = f2bf(zv - bf2f((unsigned short)hi));                   \
                zP[(g * 4 + r) * 132 + (2 * w + ntl) * 16 + rowl] = hi | (lo << 16);     \
            }                                                                            \
        }                                                                                \
        sbar();                                                                          \
        /* ---- Phase 2: [ff1|ff2|ta|tb] = z @ Wg ---- */                                \
        short8 zh[4], zl[4];                                                             \
        _Pragma("unroll")                                                                \
        for (int ks = 0; ks < 4; ++ks) {                                                 \
            const unsigned int* p = &zP[rowl * 132 + ks * 32 + g * 8];                   \
            unpack8(*(const uint4*)p, *(const uint4*)(p + 4), &zh[ks], &zl[ks]);         \
        }                                                                                \
        f32x4 fa[4], fb[4];                                                              \
        fa[0] = (f32x4){bias1, bias1, bias1, bias1};                                     \
        fa[1] = (f32x4){bias2, bias2, bias2, bias2};                                     \
        fa[2] = (f32x4){biast, biast, biast, biast};                                     \
        fa[3] = (f32x4){0.f, 0.f, 0.f, 0.f};                                             \
        _Pragma("unroll")                                                                \
        for (int m = 0; m < 4; ++m) {                                                    \
            fb[m] = (f32x4){0.f, 0.f, 0.f, 0.f};                                         \
            _Pragma("unroll")                                                            \
            for (int ks = 0; ks < 4; ++ks) {                                             \
                fa[m] = __builtin_amdgcn_mfma_f32_16x16x32_bf16(zl[ks], wg_r[m][ks], fa[m], 0, 0, 0); \
                fb[m] = __builtin_amdgcn_mfma_f32_16x16x32_bf16(zh[ks], wg_r[m][ks], fb[m], 0, 0, 0); \
            }                                                                            \
        }                                                                                \
        _Pragma("unroll")                                                                \
        for (int r = 0; r < 4; ++r) {                                                    \
            float f1 = fast_tanh(fa[0][r] + fb[0][r]);                                   \
            float f2v = fast_tanh(fa[1][r] + fb[1][r]);                                  \
            float tt = fast_sigmoid(fa[2][r] + fb[2][r] + fa[3][r] + fb[3][r]);          \
            float hv = f1 * (1.f - tt) + tt * f2v;                                       \
            hidv[r] = hv;                                                                \
            unsigned int hi = f2bf(hv);                                                  \
            unsigned int lo = f2bf(hv - bf2f((unsigned short)hi));                       \
            hidP[(g * 4 + r) * 68 + cc] = hi | (lo << 16);                               \
        }                                                                                \
        sbar();                                                                          \
    }

    #pragma unroll 1
    for (int t = 0; t < 64; t += 2) {
        RNN_STEP(t, upfA)
        RNN_STEP(t + 1, upfB)
    }
#undef RNN_STEP

    #pragma unroll
    for (int r = 0; r < 4; ++r)
        hid_out[(g * 4 + r) * 64 + cc] = hidv[r];
}

// ---------------- head ----------------
__global__ void head_kernel(const float* __restrict__ hid, const float* __restrict__ Wout,
                            const float* __restrict__ bout, float* __restrict__ out) {
    int tid = threadIdx.x;           // 128 = 16*8
    int b = tid >> 3, a = tid & 7;
    float s = bout[a];
    #pragma unroll
    for (int j = 0; j < 64; ++j) s += hid[b * 64 + j] * Wout[j * 8 + a];
    out[tid] = s;
}

extern "C" void kernel_launch(void* const* d_in, const int* in_sizes, int n_in,
                              void* d_out, int out_size, void* d_ws, size_t ws_size,
                              hipStream_t stream) {
    const float* x    = (const float*)d_in[0];
    const float* w1   = (const float*)d_in[1];
    const float* b1   = (const float*)d_in[2];
    const float* w2   = (const float*)d_in[3];
    const float* b2   = (const float*)d_in[4];
    const float* Wbb  = (const float*)d_in[5];
    const float* bbb  = (const float*)d_in[6];
    const float* Wff1 = (const float*)d_in[7];
    const float* bff1 = (const float*)d_in[8];
    const float* Wff2 = (const float*)d_in[9];
    const float* bff2 = (const float*)d_in[10];
    const float* Wta  = (const float*)d_in[11];
    const float* bta  = (const float*)d_in[12];
    const float* Wtb  = (const float*)d_in[13];
    const float* btb  = (const float*)d_in[14];
    const float* Wout = (const float*)d_in[15];
    const float* bout = (const float*)d_in[16];

    if (ws_size < (size_t)WS_BYTES) return;

    char* wsb = (char*)d_ws;
    unsigned short* w1f   = (unsigned short*)(wsb + OFF_W1F);
    unsigned short* w2f   = (unsigned short*)(wsb + OFF_W2F);
    unsigned short* wbbf  = (unsigned short*)(wsb + OFF_WBBF);
    unsigned short* h1b   = (unsigned short*)(wsb + OFF_H1B);
    unsigned short* featb = (unsigned short*)(wsb + OFF_FEATB);
    float*          u     = (float*)(wsb + OFF_U);
    float*          part  = (float*)(wsb + OFF_PART);
    float*          hid   = (float*)(wsb + OFF_HID);
    unsigned short* whf   = (unsigned short*)(wsb + OFF_WHF);
    unsigned short* wgf   = (unsigned short*)(wsb + OFF_WGF);

    prep_w1f <<<8, 256, 0, stream>>>(w1, w1f);
    prep_w2f <<<128, 256, 0, stream>>>(w2, w2f);
    prep_wbbf<<<6272, 256, 0, stream>>>(Wbb, wbbf);
    prep_whf <<<32, 256, 0, stream>>>(Wbb, whf);
    prep_wgf <<<128, 256, 0, stream>>>(Wff1, Wff2, Wta, Wtb, wgf);
    conv1_mfma<<<1024, 256, 0, stream>>>(x, b1, w1f, h1b);
    conv2_mfma<<<1024, 256, 0, stream>>>(h1b, b2, w2f, featb);
    gemm_u_mfma<<<dim3(16, 28), 256, 0, stream>>>(featb, wbbf, part);
    reduce_u<<<512, 256, 0, stream>>>(part, bbb, u);
    rnn_mfma<<<1, 256, 0, stream>>>(u, whf, wgf, bff1, bff2, bta, btb, hid);
    head_kernel<<<1, 128, 0, stream>>>(hid, Wout, bout, (float*)d_out);
}